// Round 7
// baseline (286.904 us; speedup 1.0000x reference)
//
#include <hip/hip_runtime.h>

typedef unsigned short u16;
typedef short s16x8 __attribute__((ext_vector_type(8)));
typedef float f32x4 __attribute__((ext_vector_type(4)));
typedef unsigned short u16x8 __attribute__((ext_vector_type(8)));

#define B_   8
#define N_   24000
#define M_   6000
#define K_   32
#define CIN  64
#define CMID 128
#define COUT 256
#define KP1  96   // 67 zero-padded to 3x32 for MFMA K-steps

// Static device globals — no ws_size assumption, graph-capture safe,
// fully rewritten on every call. Weights in MFMA fragment order.
__device__ __align__(16) u16 g_W1f[CMID * KP1];                 // 24.6 KB bf16
__device__ __align__(16) u16 g_W2f[COUT * CMID];                // 65.5 KB bf16
__device__ __align__(16) u16 g_Yf[(size_t)B_ * N_ * COUT];      // 98.3 MB bf16

__device__ __forceinline__ float bf2f(u16 u) {
    return __uint_as_float(((unsigned)u) << 16);
}
__device__ __forceinline__ u16 f2bf(float f) {  // fp32 -> bf16 RNE
    unsigned u = __float_as_uint(f);
    u += 0x7FFFu + ((u >> 16) & 1u);
    return (u16)(u >> 16);
}

// ---------------------------------------------------------------------------
// Kernel 0: convert fp32 weights to bf16 in fragment order.
// ---------------------------------------------------------------------------
__global__ void prep_weights(const float* __restrict__ W1,
                             const float* __restrict__ W2) {
    int t = blockIdx.x * 256 + threadIdx.x;   // 0..45055
    if (t < CMID * KP1) {                     // 12288 -> W1f
        int blk = t >> 9, off = t & 511;
        int L = off >> 3, j = off & 7;
        int ln = L & 15, quad = L >> 4;
        int w = blk / 6, r = blk % 6;
        int k0i = r >> 1, mt = r & 1;
        int row = w * 32 + mt * 16 + ln;
        int col = k0i * 32 + quad * 8 + j;
        g_W1f[t] = (col < 67) ? f2bf(W1[row * 67 + col]) : (u16)0;
    } else {                                  // 32768 -> W2f
        int i = t - CMID * KP1;
        int blk = i >> 9, off = i & 511;
        int L = off >> 3, j = off & 7;
        int ln = L & 15, quad = L >> 4;
        int w = blk >> 4, r = blk & 15;
        int k0i = r >> 2, mt = r & 3;
        int row = w * 64 + mt * 16 + ln;
        int col = k0i * 32 + quad * 8 + j;
        g_W2f[i] = f2bf(W2[row * 128 + col]);
    }
}

// ---------------------------------------------------------------------------
// Kernel 1: fused conv1+relu+conv2+relu (UNCHANGED from R6 — its counters
// arrive next round once gather drops below it in the top-5).
// ---------------------------------------------------------------------------
__global__ __launch_bounds__(256) void conv_fused(
        const float* __restrict__ feat, const float* __restrict__ xyz,
        const float* __restrict__ b1,  const float* __restrict__ b2) {
    __shared__ __align__(16) u16 sm[16896];
    u16* Xs = sm;
    u16* Hs = sm + 6656;
    u16* Ys = sm;

    const int tid  = threadIdx.x;
    const int b    = blockIdx.y;
    const int n0   = blockIdx.x * 64;
    const int w    = tid >> 6;
    const int L    = tid & 63;
    const int ln   = L & 15;
    const int quad = L >> 4;

    if (tid < 64) {
        uint4 z; z.x = z.y = z.z = z.w = 0u;
        u16* xr = Xs + tid * 104;
        *(uint4*)(xr + 64) = z; *(uint4*)(xr + 72) = z;
        *(uint4*)(xr + 80) = z; *(uint4*)(xr + 88) = z;
        const float* s = xyz + (size_t)(b * N_ + n0 + tid) * 3;
        xr[64] = f2bf(s[0]); xr[65] = f2bf(s[1]); xr[66] = f2bf(s[2]);
    }
#pragma unroll
    for (int it = 0; it < 4; ++it) {
        int idx = it * 256 + tid;
        int c   = idx >> 4;
        int p0  = (idx & 15) << 2;
        float4 v = *(const float4*)(feat + (size_t)(b * CIN + c) * N_ + n0 + p0);
        u16* dst = Xs + p0 * 104 + c;
        dst[0]   = f2bf(v.x);
        dst[104] = f2bf(v.y);
        dst[208] = f2bf(v.z);
        dst[312] = f2bf(v.w);
    }
    __syncthreads();

    f32x4 acc1[2][4];
#pragma unroll
    for (int mt = 0; mt < 2; ++mt)
#pragma unroll
        for (int nt = 0; nt < 4; ++nt) {
            f32x4 zz = {0.f, 0.f, 0.f, 0.f};
            acc1[mt][nt] = zz;
        }
#pragma unroll
    for (int k0i = 0; k0i < 3; ++k0i) {
        s16x8 af[2], xf[4];
#pragma unroll
        for (int mt = 0; mt < 2; ++mt)
            af[mt] = *(const s16x8*)(g_W1f + (((w * 3 + k0i) * 2 + mt) << 9) + L * 8);
#pragma unroll
        for (int nt = 0; nt < 4; ++nt)
            xf[nt] = *(const s16x8*)(Xs + (nt * 16 + ln) * 104 + k0i * 32 + quad * 8);
#pragma unroll
        for (int mt = 0; mt < 2; ++mt)
#pragma unroll
            for (int nt = 0; nt < 4; ++nt)
                acc1[mt][nt] = __builtin_amdgcn_mfma_f32_16x16x32_bf16(
                    af[mt], xf[nt], acc1[mt][nt], 0, 0, 0);
    }
#pragma unroll
    for (int mt = 0; mt < 2; ++mt) {
        int m0 = w * 32 + mt * 16 + quad * 4;
        float4 bv = *(const float4*)(b1 + m0);
#pragma unroll
        for (int nt = 0; nt < 4; ++nt) {
            int p = nt * 16 + ln;
            float x0 = acc1[mt][nt][0] + bv.x;
            float x1 = acc1[mt][nt][1] + bv.y;
            float x2 = acc1[mt][nt][2] + bv.z;
            float x3 = acc1[mt][nt][3] + bv.w;
            ushort4 hv;
            hv.x = f2bf(x0 > 0.f ? x0 : 0.f);
            hv.y = f2bf(x1 > 0.f ? x1 : 0.f);
            hv.z = f2bf(x2 > 0.f ? x2 : 0.f);
            hv.w = f2bf(x3 > 0.f ? x3 : 0.f);
            *(ushort4*)(Hs + p * 136 + m0) = hv;
        }
    }
    __syncthreads();

    f32x4 acc2[4][4];
#pragma unroll
    for (int mt = 0; mt < 4; ++mt)
#pragma unroll
        for (int nt = 0; nt < 4; ++nt) {
            f32x4 zz = {0.f, 0.f, 0.f, 0.f};
            acc2[mt][nt] = zz;
        }
#pragma unroll
    for (int k0i = 0; k0i < 4; ++k0i) {
        s16x8 af[4], hf[4];
#pragma unroll
        for (int mt = 0; mt < 4; ++mt)
            af[mt] = *(const s16x8*)(g_W2f + (((w * 4 + k0i) * 4 + mt) << 9) + L * 8);
#pragma unroll
        for (int nt = 0; nt < 4; ++nt)
            hf[nt] = *(const s16x8*)(Hs + (nt * 16 + ln) * 136 + k0i * 32 + quad * 8);
#pragma unroll
        for (int mt = 0; mt < 4; ++mt)
#pragma unroll
            for (int nt = 0; nt < 4; ++nt)
                acc2[mt][nt] = __builtin_amdgcn_mfma_f32_16x16x32_bf16(
                    af[mt], hf[nt], acc2[mt][nt], 0, 0, 0);
    }
    __syncthreads();

#pragma unroll
    for (int mt = 0; mt < 4; ++mt) {
        int c0 = w * 64 + mt * 16 + quad * 4;
        float4 bv = *(const float4*)(b2 + c0);
#pragma unroll
        for (int nt = 0; nt < 4; ++nt) {
            int p = nt * 16 + ln;
            float x0 = acc2[mt][nt][0] + bv.x;
            float x1 = acc2[mt][nt][1] + bv.y;
            float x2 = acc2[mt][nt][2] + bv.z;
            float x3 = acc2[mt][nt][3] + bv.w;
            ushort4 yv;
            yv.x = f2bf(x0 > 0.f ? x0 : 0.f);
            yv.y = f2bf(x1 > 0.f ? x1 : 0.f);
            yv.z = f2bf(x2 > 0.f ? x2 : 0.f);
            yv.w = f2bf(x3 > 0.f ? x3 : 0.f);
            *(ushort4*)(Ys + p * 264 + c0) = yv;
        }
    }
    __syncthreads();

    u16* dstY = g_Yf + ((size_t)b * N_ + n0) * COUT;
#pragma unroll
    for (int i = 0; i < 8; ++i) {
        int g = i * 256 + tid;
        int p = g >> 5, c16 = g & 31;
        *(uint4*)(dstY + (size_t)p * COUT + c16 * 8) =
            *(const uint4*)(Ys + p * 264 + c16 * 8);
    }
}

// ---------------------------------------------------------------------------
// Kernel 2: gather + max, MLP-restructured.
// R6 evidence: 54 cyc/row-load issue rate => ~0.8 loads in flight per wave
// (compiler serialized load->waitcnt->max). Fix:
//  * half-wave per row: lane L (half h=L>>5, li=L&31) reads 16B = channels
//    li*8..+7; halves read DIFFERENT neighbors -> 2 rows (8 lines) per instr.
//  * per query: 16 idx via 4x ds_read_b128, loads issued in 2 batches of 8
//    uint4s held in registers before consumption -> >=8 loads in flight.
//  * max via __builtin_elementwise_max on ushort8 (v_pk_max_u16); halves
//    combined with 4x __shfl_xor(..,32). Post-ReLU bf16 (sign=0) is
//    order-isomorphic to u16 -> exact bf16 max.
// ---------------------------------------------------------------------------
__global__ __launch_bounds__(256) void gather_max(
        const int* __restrict__ nbr, float* __restrict__ out) {
    __shared__ __align__(16) int sidx[32 * K_];    // 4 KB
    __shared__ __align__(16) u16 ymax[COUT * 36];  // 18.4 KB, [c][m] stride 36

    const int tid = threadIdx.x;
    const int b   = blockIdx.y;
    const int m0  = blockIdx.x * 32;

    if (m0 + (tid >> 3) < M_)
        *(int4*)(sidx + tid * 4) =
            *(const int4*)(nbr + ((size_t)b * M_ + m0) * K_ + tid * 4);
    __syncthreads();

    const int w  = tid >> 6;
    const int L  = tid & 63;
    const int h  = L >> 5;           // half id: which neighbor this lane serves
    const int li = L & 31;           // lane-in-half: channels li*8..li*8+7
    const u16* base = g_Yf + (size_t)b * N_ * COUT + li * 8;

#pragma unroll
    for (int i = 0; i < 8; ++i) {
        int ml = w * 8 + i;
        if (m0 + ml >= M_) break;

        // this lane's 16 neighbor indices: k = g*8 + h*4 + {0..3}, g=0..3
        const int* sp = sidx + ml * K_ + h * 4;
        int4 i0 = *(const int4*)(sp);
        int4 i1 = *(const int4*)(sp + 8);
        int4 i2 = *(const int4*)(sp + 16);
        int4 i3 = *(const int4*)(sp + 24);
        int idx[16] = {i0.x, i0.y, i0.z, i0.w, i1.x, i1.y, i1.z, i1.w,
                       i2.x, i2.y, i2.z, i2.w, i3.x, i3.y, i3.z, i3.w};

        u16x8 mx = (u16x8)0;
#pragma unroll
        for (int g = 0; g < 2; ++g) {
            u16x8 v[8];
#pragma unroll
            for (int t = 0; t < 8; ++t) {
                unsigned id = (unsigned)idx[g * 8 + t];
                id = id < (unsigned)N_ ? id : 0u;            // defensive clamp
                v[t] = *(const u16x8*)(base + (size_t)id * COUT);
            }
#pragma unroll
            for (int t = 0; t < 8; ++t)
                mx = __builtin_elementwise_max(mx, v[t]);
        }

        // combine the two halves (each has max over its 16 k-values)
        int4 tmp = *(int4*)&mx;
        tmp.x = __shfl_xor(tmp.x, 32);
        tmp.y = __shfl_xor(tmp.y, 32);
        tmp.z = __shfl_xor(tmp.z, 32);
        tmp.w = __shfl_xor(tmp.w, 32);
        u16x8 other = *(u16x8*)&tmp;
        mx = __builtin_elementwise_max(mx, other);

        // both halves hold the full result; split the transpose-writes:
        // half 0 writes channels cbase..+3, half 1 writes cbase+4..+7
        unsigned a0 = h ? ((uint4*)&mx)->z : ((uint4*)&mx)->x;
        unsigned a1 = h ? ((uint4*)&mx)->w : ((uint4*)&mx)->y;
        u16* yp = ymax + (li * 8 + h * 4) * 36 + ml;
        yp[0]   = (u16)a0; yp[36]  = (u16)(a0 >> 16);
        yp[72]  = (u16)a1; yp[108] = (u16)(a1 >> 16);
    }
    __syncthreads();

    // transpose out of LDS, expand bf16 -> fp32: out[b][c][m0..m0+31]
    int valid = M_ - m0; if (valid > 32) valid = 32;
#pragma unroll
    for (int i = 0; i < 8; ++i) {
        int c  = i * 32 + (tid >> 3);
        int mc = (tid & 7) << 2;
        if (mc + 4 <= valid) {
            const u16* src = ymax + c * 36 + mc;
            float4 v;
            v.x = bf2f(src[0]); v.y = bf2f(src[1]);
            v.z = bf2f(src[2]); v.w = bf2f(src[3]);
            *(float4*)(out + (size_t)(b * COUT + c) * M_ + m0 + mc) = v;
        }
    }
}

extern "C" void kernel_launch(void* const* d_in, const int* in_sizes, int n_in,
                              void* d_out, int out_size, void* d_ws, size_t ws_size,
                              hipStream_t stream) {
    // inputs (all fp32 except neighbor_idx int32):
    // 0=query_xyz(unused) 1=support_xyz 2=features 3=neighbor_idx
    // 4=W1 5=b1 6=W2 7=b2. Output: fp32 [B][C_OUT][M].
    const float* xyz  = (const float*)d_in[1];
    const float* feat = (const float*)d_in[2];
    const int*   nbr  = (const int*)d_in[3];
    const float* W1   = (const float*)d_in[4];
    const float* b1   = (const float*)d_in[5];
    const float* W2   = (const float*)d_in[6];
    const float* b2   = (const float*)d_in[7];
    float* out = (float*)d_out;
    (void)d_ws; (void)ws_size;

    prep_weights<<<176, 256, 0, stream>>>(W1, W2);
    conv_fused<<<dim3(N_ / 64, B_), 256, 0, stream>>>(feat, xyz, b1, b2);
    gather_max<<<dim3((M_ + 31) / 32, B_), 256, 0, stream>>>(nbr, out);
}

// Round 8
// 266.994 us; speedup vs baseline: 1.0746x; 1.0746x over previous
//
#include <hip/hip_runtime.h>

typedef unsigned short u16;
typedef short s16x8 __attribute__((ext_vector_type(8)));
typedef float f32x4 __attribute__((ext_vector_type(4)));
typedef unsigned short u16x8 __attribute__((ext_vector_type(8)));

#define B_   8
#define N_   24000
#define M_   6000
#define K_   32
#define CIN  64
#define CMID 128
#define COUT 256
#define KP1  96    // 67 zero-padded to 3x32 for MFMA K-steps
#define QB_  188   // ceil(M/32) query-blocks per (batch, quarter) combo

// Static device globals — no ws_size assumption, graph-capture safe,
// fully rewritten on every call. Weights in MFMA fragment order.
__device__ __align__(16) u16 g_W1f[CMID * KP1];                 // 24.6 KB bf16
__device__ __align__(16) u16 g_W2f[COUT * CMID];                // 65.5 KB bf16
__device__ __align__(16) u16 g_Yf[(size_t)B_ * N_ * COUT];      // 98.3 MB bf16

__device__ __forceinline__ float bf2f(u16 u) {
    return __uint_as_float(((unsigned)u) << 16);
}
__device__ __forceinline__ u16 f2bf(float f) {  // fp32 -> bf16 RNE
    unsigned u = __float_as_uint(f);
    u += 0x7FFFu + ((u >> 16) & 1u);
    return (u16)(u >> 16);
}

// ---------------------------------------------------------------------------
// Kernel 0: convert fp32 weights to bf16 in fragment order. (unchanged)
// ---------------------------------------------------------------------------
__global__ void prep_weights(const float* __restrict__ W1,
                             const float* __restrict__ W2) {
    int t = blockIdx.x * 256 + threadIdx.x;   // 0..45055
    if (t < CMID * KP1) {                     // 12288 -> W1f
        int blk = t >> 9, off = t & 511;
        int L = off >> 3, j = off & 7;
        int ln = L & 15, quad = L >> 4;
        int w = blk / 6, r = blk % 6;
        int k0i = r >> 1, mt = r & 1;
        int row = w * 32 + mt * 16 + ln;
        int col = k0i * 32 + quad * 8 + j;
        g_W1f[t] = (col < 67) ? f2bf(W1[row * 67 + col]) : (u16)0;
    } else {                                  // 32768 -> W2f
        int i = t - CMID * KP1;
        int blk = i >> 9, off = i & 511;
        int L = off >> 3, j = off & 7;
        int ln = L & 15, quad = L >> 4;
        int w = blk >> 4, r = blk & 15;
        int k0i = r >> 2, mt = r & 3;
        int row = w * 64 + mt * 16 + ln;
        int col = k0i * 32 + quad * 8 + j;
        g_W2f[i] = f2bf(W2[row * 128 + col]);
    }
}

// ---------------------------------------------------------------------------
// Kernel 1: fused conv1+relu+conv2+relu (BYTE-IDENTICAL to R7 — once gather
// drops below it, its counters surface in the top-5 for a theory-led edit).
// ---------------------------------------------------------------------------
__global__ __launch_bounds__(256) void conv_fused(
        const float* __restrict__ feat, const float* __restrict__ xyz,
        const float* __restrict__ b1,  const float* __restrict__ b2) {
    __shared__ __align__(16) u16 sm[16896];
    u16* Xs = sm;
    u16* Hs = sm + 6656;
    u16* Ys = sm;

    const int tid  = threadIdx.x;
    const int b    = blockIdx.y;
    const int n0   = blockIdx.x * 64;
    const int w    = tid >> 6;
    const int L    = tid & 63;
    const int ln   = L & 15;
    const int quad = L >> 4;

    if (tid < 64) {
        uint4 z; z.x = z.y = z.z = z.w = 0u;
        u16* xr = Xs + tid * 104;
        *(uint4*)(xr + 64) = z; *(uint4*)(xr + 72) = z;
        *(uint4*)(xr + 80) = z; *(uint4*)(xr + 88) = z;
        const float* s = xyz + (size_t)(b * N_ + n0 + tid) * 3;
        xr[64] = f2bf(s[0]); xr[65] = f2bf(s[1]); xr[66] = f2bf(s[2]);
    }
#pragma unroll
    for (int it = 0; it < 4; ++it) {
        int idx = it * 256 + tid;
        int c   = idx >> 4;
        int p0  = (idx & 15) << 2;
        float4 v = *(const float4*)(feat + (size_t)(b * CIN + c) * N_ + n0 + p0);
        u16* dst = Xs + p0 * 104 + c;
        dst[0]   = f2bf(v.x);
        dst[104] = f2bf(v.y);
        dst[208] = f2bf(v.z);
        dst[312] = f2bf(v.w);
    }
    __syncthreads();

    f32x4 acc1[2][4];
#pragma unroll
    for (int mt = 0; mt < 2; ++mt)
#pragma unroll
        for (int nt = 0; nt < 4; ++nt) {
            f32x4 zz = {0.f, 0.f, 0.f, 0.f};
            acc1[mt][nt] = zz;
        }
#pragma unroll
    for (int k0i = 0; k0i < 3; ++k0i) {
        s16x8 af[2], xf[4];
#pragma unroll
        for (int mt = 0; mt < 2; ++mt)
            af[mt] = *(const s16x8*)(g_W1f + (((w * 3 + k0i) * 2 + mt) << 9) + L * 8);
#pragma unroll
        for (int nt = 0; nt < 4; ++nt)
            xf[nt] = *(const s16x8*)(Xs + (nt * 16 + ln) * 104 + k0i * 32 + quad * 8);
#pragma unroll
        for (int mt = 0; mt < 2; ++mt)
#pragma unroll
            for (int nt = 0; nt < 4; ++nt)
                acc1[mt][nt] = __builtin_amdgcn_mfma_f32_16x16x32_bf16(
                    af[mt], xf[nt], acc1[mt][nt], 0, 0, 0);
    }
#pragma unroll
    for (int mt = 0; mt < 2; ++mt) {
        int m0 = w * 32 + mt * 16 + quad * 4;
        float4 bv = *(const float4*)(b1 + m0);
#pragma unroll
        for (int nt = 0; nt < 4; ++nt) {
            int p = nt * 16 + ln;
            float x0 = acc1[mt][nt][0] + bv.x;
            float x1 = acc1[mt][nt][1] + bv.y;
            float x2 = acc1[mt][nt][2] + bv.z;
            float x3 = acc1[mt][nt][3] + bv.w;
            ushort4 hv;
            hv.x = f2bf(x0 > 0.f ? x0 : 0.f);
            hv.y = f2bf(x1 > 0.f ? x1 : 0.f);
            hv.z = f2bf(x2 > 0.f ? x2 : 0.f);
            hv.w = f2bf(x3 > 0.f ? x3 : 0.f);
            *(ushort4*)(Hs + p * 136 + m0) = hv;
        }
    }
    __syncthreads();

    f32x4 acc2[4][4];
#pragma unroll
    for (int mt = 0; mt < 4; ++mt)
#pragma unroll
        for (int nt = 0; nt < 4; ++nt) {
            f32x4 zz = {0.f, 0.f, 0.f, 0.f};
            acc2[mt][nt] = zz;
        }
#pragma unroll
    for (int k0i = 0; k0i < 4; ++k0i) {
        s16x8 af[4], hf[4];
#pragma unroll
        for (int mt = 0; mt < 4; ++mt)
            af[mt] = *(const s16x8*)(g_W2f + (((w * 4 + k0i) * 4 + mt) << 9) + L * 8);
#pragma unroll
        for (int nt = 0; nt < 4; ++nt)
            hf[nt] = *(const s16x8*)(Hs + (nt * 16 + ln) * 136 + k0i * 32 + quad * 8);
#pragma unroll
        for (int mt = 0; mt < 4; ++mt)
#pragma unroll
            for (int nt = 0; nt < 4; ++nt)
                acc2[mt][nt] = __builtin_amdgcn_mfma_f32_16x16x32_bf16(
                    af[mt], hf[nt], acc2[mt][nt], 0, 0, 0);
    }
    __syncthreads();

#pragma unroll
    for (int mt = 0; mt < 4; ++mt) {
        int c0 = w * 64 + mt * 16 + quad * 4;
        float4 bv = *(const float4*)(b2 + c0);
#pragma unroll
        for (int nt = 0; nt < 4; ++nt) {
            int p = nt * 16 + ln;
            float x0 = acc2[mt][nt][0] + bv.x;
            float x1 = acc2[mt][nt][1] + bv.y;
            float x2 = acc2[mt][nt][2] + bv.z;
            float x3 = acc2[mt][nt][3] + bv.w;
            ushort4 yv;
            yv.x = f2bf(x0 > 0.f ? x0 : 0.f);
            yv.y = f2bf(x1 > 0.f ? x1 : 0.f);
            yv.z = f2bf(x2 > 0.f ? x2 : 0.f);
            yv.w = f2bf(x3 > 0.f ? x3 : 0.f);
            *(ushort4*)(Ys + p * 264 + c0) = yv;
        }
    }
    __syncthreads();

    u16* dstY = g_Yf + ((size_t)b * N_ + n0) * COUT;
#pragma unroll
    for (int i = 0; i < 8; ++i) {
        int g = i * 256 + tid;
        int p = g >> 5, c16 = g & 31;
        *(uint4*)(dstY + (size_t)p * COUT + c16 * 8) =
            *(const uint4*)(Ys + p * 264 + c16 * 8);
    }
}

// ---------------------------------------------------------------------------
// Kernel 2: gather + max, L2-locality version.
// R5-R7 all plateau at ~136 µs / 443 MB L2-miss traffic: the 12.3 MB
// per-batch Yf slab thrashes the 4 MB per-XCD L2 (56% miss). Fix: split
// channels into quarters -> per-(b,q) slab = 24000 x 64ch x 2B = 3.07 MB,
// fits one XCD's L2 with reuse factor 8. 1D grid, XCD-swizzled
// (blockIdx&7 = XCD via the %8 round-robin heuristic): each XCD works
// through its 4 (b,q) combos in dispatch order, keeping ~one slab hot.
// LDS deliberately ~29.6 KB -> 5 blocks/CU -> <=160 blocks/XCD < 188/combo,
// limiting combo-mixing. Row = 128 B = 8 lanes x 16 B; wave covers 8
// neighbors/instr; k-reduce: per-lane pk_max over 4 rounds + shfl_xor
// 8/16/32. Max in u16 domain (post-ReLU bf16, sign=0) = exact bf16 max.
// ---------------------------------------------------------------------------
__global__ __launch_bounds__(256) void gather_max(
        const int* __restrict__ nbr, float* __restrict__ out) {
    __shared__ __align__(16) int sidx[32 * K_];    // 4 KB
    __shared__ __align__(16) u16 ymax[32 * 400];   // 25.6 KB, [m][c] stride 400

    const int tid = threadIdx.x;
    const int l   = blockIdx.x;
    const int xcd = l & 7;
    const int j   = l >> 3;          // 0..751
    const int cw  = j / QB_;         // combo-within-XCD 0..3
    const int qb  = j % QB_;         // query-block 0..187
    const int combo = cw * 8 + xcd;  // 0..31
    const int b   = combo >> 2;
    const int q   = combo & 3;       // channel quarter (64 ch)
    const int m0  = qb * 32;

    // stage neighbor indices: 32 queries x 32 k
    if (m0 + (tid >> 3) < M_)
        *(int4*)(sidx + tid * 4) =
            *(const int4*)(nbr + ((size_t)b * M_ + m0) * K_ + tid * 4);
    __syncthreads();

    const int w  = tid >> 6;         // wave 0..3
    const int L  = tid & 63;
    const int kg = L >> 3;           // k-group 0..7 (neighbor within round)
    const int co = L & 7;            // channel octet within quarter
    const u16* base = g_Yf + (size_t)b * N_ * COUT + q * 64 + co * 8;

#pragma unroll
    for (int i = 0; i < 8; ++i) {
        int ml = w * 8 + i;
        if (m0 + ml < M_) {
            // 4 independent idx reads, then 4 independent row loads (MLP=4)
            int id[4];
#pragma unroll
            for (int r = 0; r < 4; ++r)
                id[r] = sidx[ml * K_ + r * 8 + kg];
            u16x8 v[4];
#pragma unroll
            for (int r = 0; r < 4; ++r) {
                unsigned u = (unsigned)id[r];
                u = u < (unsigned)N_ ? u : 0u;   // defensive clamp
                v[r] = *(const u16x8*)(base + (size_t)u * COUT);
            }
            u16x8 mx = __builtin_elementwise_max(
                __builtin_elementwise_max(v[0], v[1]),
                __builtin_elementwise_max(v[2], v[3]));

            // reduce across the 8 k-groups (lane bits 3,4,5)
#pragma unroll
            for (int mask = 8; mask <= 32; mask <<= 1) {
                int4 t = *(int4*)&mx;
                t.x = __shfl_xor(t.x, mask);
                t.y = __shfl_xor(t.y, mask);
                t.z = __shfl_xor(t.z, mask);
                t.w = __shfl_xor(t.w, mask);
                mx = __builtin_elementwise_max(mx, *(u16x8*)&t);
            }
            if (kg == 0)   // one replicate writes 8 channels, 16B ds_write
                *(u16x8*)(ymax + ml * 400 + co * 8) = mx;
        }
    }
    __syncthreads();

    // transpose + bf16->fp32: out[b][q*64+c][m0..m0+31]
    int valid = M_ - m0; if (valid > 32) valid = 32;
#pragma unroll
    for (int it = 0; it < 2; ++it) {
        int c  = it * 32 + (tid >> 3);   // local channel 0..63
        int mc = (tid & 7) << 2;
        if (mc + 4 <= valid) {
            float4 v;
            v.x = bf2f(ymax[(mc + 0) * 400 + c]);
            v.y = bf2f(ymax[(mc + 1) * 400 + c]);
            v.z = bf2f(ymax[(mc + 2) * 400 + c]);
            v.w = bf2f(ymax[(mc + 3) * 400 + c]);
            *(float4*)(out + (size_t)(b * COUT + q * 64 + c) * M_ + m0 + mc) = v;
        }
    }
}

extern "C" void kernel_launch(void* const* d_in, const int* in_sizes, int n_in,
                              void* d_out, int out_size, void* d_ws, size_t ws_size,
                              hipStream_t stream) {
    // inputs (all fp32 except neighbor_idx int32):
    // 0=query_xyz(unused) 1=support_xyz 2=features 3=neighbor_idx
    // 4=W1 5=b1 6=W2 7=b2. Output: fp32 [B][C_OUT][M].
    const float* xyz  = (const float*)d_in[1];
    const float* feat = (const float*)d_in[2];
    const int*   nbr  = (const int*)d_in[3];
    const float* W1   = (const float*)d_in[4];
    const float* b1   = (const float*)d_in[5];
    const float* W2   = (const float*)d_in[6];
    const float* b2   = (const float*)d_in[7];
    float* out = (float*)d_out;
    (void)d_ws; (void)ws_size;

    prep_weights<<<176, 256, 0, stream>>>(W1, W2);
    conv_fused<<<dim3(N_ / 64, B_), 256, 0, stream>>>(feat, xyz, b1, b2);
    gather_max<<<32 * QB_, 256, 0, stream>>>(nbr, out);   // 6016 blocks
}